// Round 5
// baseline (688.288 us; speedup 1.0000x reference)
//
#include <hip/hip_runtime.h>
#include <hip/hip_bf16.h>
#include <cstdint>

// Problem constants
#define B_     2
#define N_     100000
#define C_     256
#define H_     8
#define D_     64
#define S_     64
#define INNER_ 512

#define TILE_T 64
#define NTILES ((N_ + TILE_T - 1) / TILE_T)   // 1563
#define PBLK   32                             // blocks per (b,h); grid = 32*8*2 = 512 = 2/CU

// LDS strides (shorts). 260 = 130 dw == 2 mod 32; 68 = 34 dw == 2 mod 32:
// row-strided b128 reads / uint2 writes start at 16 distinct banks per
// 16-lane phase (<=2-way aliasing = free) instead of the old 264/72
// (132/36 dw == 4 mod 32 -> 8 bank-groups -> ~4-way serialization).
#define XS_STR 260
#define WS_STR 68

// Workspace layout (bytes)
#define WEFFT_OFF 0                           // bf16 [H][S][C]   = 262144  (pre-scaled by log2e/temp)
#define WFXT_OFF  262144                      // bf16 [H][D][C]   = 262144
#define BIASE_OFF 524288                      // f32  [H][S]      = 2048    (pre-scaled)
#define SLAB_OFF  526336                      // f32 [B*H][PBLK][4096] = 8388608
#define NSLAB_OFF (SLAB_OFF + B_*H_*PBLK*4096*4)
#define WS_BIG_END (NSLAB_OFF + B_*H_*PBLK*64*4)   // ~9.05 MB
#define ACC_OFF   526336
#define NRM_OFF   (ACC_OFF + B_*H_*S_*D_*4)
#define WS_SMALL_END (NRM_OFF + B_*H_*S_*4)

typedef __attribute__((ext_vector_type(8)))  short short8;
typedef __attribute__((ext_vector_type(4)))  float f32x4;

__device__ inline short f2bf(float f) {
    __hip_bfloat16 h = __float2bfloat16(f);
    short s; __builtin_memcpy(&s, &h, 2); return s;
}
__device__ inline uint32_t pk2(float a, float b) {
    __hip_bfloat162 h = __float22bfloat162_rn(float2{a, b});
    uint32_t u; __builtin_memcpy(&u, &h, 4); return u;
}

// ---------------------------------------------------------------------------
// prep: unchanged (v4).
// ---------------------------------------------------------------------------
__global__ void prep_kernel(const float* __restrict__ W_x,
                            const float* __restrict__ b_x,
                            const float* __restrict__ W_fx,
                            const float* __restrict__ W_slice,
                            const float* __restrict__ b_slice,
                            const float* __restrict__ temperature,
                            uint8_t* __restrict__ wsb) {
    int wid  = (blockIdx.x * 256 + threadIdx.x) >> 6;
    int lane = threadIdx.x & 63;
    if (wid < H_ * C_) {
        int h = wid >> 8, k = wid & 255;
        float t = temperature[h]; t = fminf(fmaxf(t, 0.1f), 5.0f);
        float sc = 1.44269504088896f / t;
        const float* wx = W_x + k * INNER_ + h * 64;
        float a = 0.f;
        #pragma unroll 8
        for (int d = 0; d < D_; ++d)
            a = fmaf(wx[d], W_slice[d * 64 + lane], a);
        ((short*)(wsb + WEFFT_OFF))[(h * 64 + lane) * 256 + k] = f2bf(a * sc);
    } else if (wid < 2 * H_ * C_) {
        int j = wid - H_ * C_;
        int h = j >> 8, k = j & 255;
        ((short*)(wsb + WFXT_OFF))[(h * 64 + lane) * 256 + k] =
            f2bf(W_fx[k * INNER_ + h * 64 + lane]);
    } else if (wid < 2 * H_ * C_ + H_) {
        int h = wid - 2 * H_ * C_;
        float t = temperature[h]; t = fminf(fmaxf(t, 0.1f), 5.0f);
        float sc = 1.44269504088896f / t;
        float a = 0.f;
        #pragma unroll 8
        for (int d = 0; d < D_; ++d)
            a = fmaf(b_x[h * 64 + d], W_slice[d * 64 + lane], a);
        ((float*)(wsb + BIASE_OFF))[h * 64 + lane] = (a + b_slice[lane]) * sc;
    }
}

// ---------------------------------------------------------------------------
// main v8 = v6 dataflow (32x32 per-wave main tile, 2x2 16x16x32 MFMAs,
// A-reads halved vs v4) at 2 blocks/CU.
//   Register fix: NO persistent breg. B-fragments are read from GLOBAL
//   (wsb weights, 512 KB total, L1/L2-resident) inside the k-loop. k-order
//   is rotated by tile (k = (kk+tile)&7, accumulation commutative) so the
//   loads are loop-VARIANT and the compiler cannot hoist them back into
//   64 registers. Budget: xv 32 + acc 16 + accO 8 + b-temps + misc ~110
//   < 128-reg cap of __launch_bounds__(512,4) -> 2 blocks/CU, restoring
//   the cross-block overlap that made v4 fast (round-4 lesson: at 1
//   block/CU barrier chains are exposed; per-tile cost ROSE 19% despite
//   36% less LDS traffic).
//   Bank-conflict fix: strides 264->260, 72->68 (see XS_STR/WS_STR).
// Roles: g = wv>>2 (0 logits/1 fx), mh = (wv>>1)&1 (token half), nh = wv&1
// (col half). Agg roles (w4 = wv&3 s-strip, g d-half) = v4. 3 barriers/tile.
// ---------------------------------------------------------------------------
template<bool SLAB>
__global__ __launch_bounds__(512, 4) void main_kernel(
        const float* __restrict__ x,
        const float* __restrict__ b_fx,
        const uint8_t* __restrict__ wsb,
        float* __restrict__ accg,
        float* __restrict__ nrmg) {
    __shared__ union {
        short xs[TILE_T * XS_STR];            // 33280 B  [tok][k] bf16
        float np[2][64];                      // endgame nrm combine
    } u;
    __shared__ short wsl[S_ * WS_STR];        // 8704 B  [s][tok] bf16
    __shared__ short fsl[D_ * WS_STR];        // 8704 B  [d][tok] bf16
    __shared__ float smB[TILE_T * 2];         // 512 B   [tok][nh] partial sumexp

    const int tid = threadIdx.x;
    const int bid = blockIdx.x;
    // XCD swizzle: 8 h-siblings of each (p,b) group share bid%8 (same XCD)
    const int cc = bid & 7;
    const int h  = (bid >> 3) & 7;
    const int pb = (bid >> 6) * 8 + cc;       // [0,64)
    const int p  = pb & 31;
    const int b  = pb >> 5;

    const int lane = tid & 63, wv = tid >> 6;
    const int l = lane & 15, q = lane >> 4;
    const int g  = wv >> 2;                   // 0: logits, 1: fx  (also agg d-half)
    const int mh = (wv >> 1) & 1;             // main: token half
    const int nh = wv & 1;                    // main: col half
    const int w4 = wv & 3;                    // agg: s-strip

    // B-fragment base pointers (global; L1/L2-resident). Two col-groups.
    const short* wT = (const short*)(wsb + (g ? WFXT_OFF : WEFFT_OFF)) + h * (64 * 256);
    const short* bp0 = wT + (nh * 32 + l) * 256 + q * 8;        // j=0 col group
    const short* bp1 = wT + (nh * 32 + 16 + l) * 256 + q * 8;   // j=1 col group

    float bias[2];
    {
        const float* bp = g ? (b_fx + h * 64)
                            : ((const float*)(wsb + BIASE_OFF) + h * 64);
        bias[0] = bp[nh * 32 + l];
        bias[1] = bp[nh * 32 + 16 + l];
    }

    const float* xb = x + (size_t)b * ((size_t)N_ * C_);
    f32x4 accO[2] = {};                       // agg out: [16 s][32 d] strip (v4)
    float nrm0 = 0.f, nrm1 = 0.f;             // per-lane norm partials

    // prologue: prefetch first tile into registers
    float4 xv[8];
    {
        const int col = lane * 4;
        #pragma unroll
        for (int j = 0; j < 8; ++j) {
            int gt = p * TILE_T + wv + 8 * j;
            xv[j] = (gt < N_) ? *(const float4*)(xb + (size_t)gt * C_ + col)
                              : float4{0.f, 0.f, 0.f, 0.f};
        }
    }

    #pragma unroll 1
    for (int tile = p; tile < NTILES; tile += PBLK) {
        // ---- pack prefetched tile -> xs. Safe without a barrier: previous
        // iteration's xs reads (main MFMA) completed before previous B3/B4,
        // and agg (between B4 and here) touches only wsl/fsl.
        #pragma unroll
        for (int j = 0; j < 8; ++j) {
            int row = wv + 8 * j;
            uint2 pk = { pk2(xv[j].x, xv[j].y), pk2(xv[j].z, xv[j].w) };
            *(uint2*)(u.xs + row * XS_STR + lane * 4) = pk;
        }
        __syncthreads();                      // B2: xs ready

        // ---- issue prefetch of NEXT tile (hides under MFMA+softmax+agg)
        {
            int nxt = tile + PBLK;
            if (nxt < NTILES) {
                const int col = lane * 4;
                #pragma unroll
                for (int j = 0; j < 8; ++j) {
                    int gt = nxt * TILE_T + wv + 8 * j;
                    xv[j] = (gt < N_) ? *(const float4*)(xb + (size_t)gt * C_ + col)
                                      : float4{0.f, 0.f, 0.f, 0.f};
                }
            }
        }

        // ---- main MFMA: 32 tok x 32 col per wave, 4 independent accumulators.
        // B-frags loaded from global per-k (tile-rotated k defeats hoisting;
        // MFMA accumulation over k is commutative).
        f32x4 acc[2][2] = {};
        #pragma unroll
        for (int kk = 0; kk < 8; ++kk) {
            const int k = (kk + tile) & 7;
            short8 b0 = *(const short8*)(bp0 + k * 32);
            short8 b1 = *(const short8*)(bp1 + k * 32);
            short8 a0 = *(const short8*)(u.xs + (mh * 32 + l) * XS_STR + k * 32 + q * 8);
            short8 a1 = *(const short8*)(u.xs + (mh * 32 + 16 + l) * XS_STR + k * 32 + q * 8);
            acc[0][0] = __builtin_amdgcn_mfma_f32_16x16x32_bf16(a0, b0, acc[0][0], 0, 0, 0);
            acc[0][1] = __builtin_amdgcn_mfma_f32_16x16x32_bf16(a0, b1, acc[0][1], 0, 0, 0);
            acc[1][0] = __builtin_amdgcn_mfma_f32_16x16x32_bf16(a1, b0, acc[1][0], 0, 0, 0);
            acc[1][1] = __builtin_amdgcn_mfma_f32_16x16x32_bf16(a1, b1, acc[1][1], 0, 0, 0);
        }

        if (g == 0) {
            // exp2 (pre-scaled log2 domain) + partial row-sum over this wave's
            // 32 s-cols (pairwise in-thread + 4-step shfl over l)
            #pragma unroll
            for (int i = 0; i < 2; ++i)
                #pragma unroll
                for (int r = 0; r < 4; ++r) {
                    float e0 = __builtin_amdgcn_exp2f(acc[i][0][r] + bias[0]);
                    float e1 = __builtin_amdgcn_exp2f(acc[i][1][r] + bias[1]);
                    acc[i][0][r] = e0;
                    acc[i][1][r] = e1;
                    float s = e0 + e1;
                    s += __shfl_xor(s, 1, 64);
                    s += __shfl_xor(s, 2, 64);
                    s += __shfl_xor(s, 4, 64);
                    s += __shfl_xor(s, 8, 64);
                    if (l == 0) smB[(mh * 32 + i * 16 + q * 4 + r) * 2 + nh] = s;
                }
        } else {
            // fx: add bias, write fsl now (no smB dependency; safe vs agg(t-1)
            // because B2 separates agg reads from these writes)
            #pragma unroll
            for (int i = 0; i < 2; ++i) {
                #pragma unroll
                for (int r = 0; r < 4; ++r) {
                    acc[i][0][r] += bias[0];
                    acc[i][1][r] += bias[1];
                }
                #pragma unroll
                for (int j = 0; j < 2; ++j) {
                    uint2 pk = { pk2(acc[i][j][0], acc[i][j][1]),
                                 pk2(acc[i][j][2], acc[i][j][3]) };
                    *(uint2*)(fsl + (nh * 32 + j * 16 + l) * WS_STR + mh * 32 + i * 16 + q * 4) = pk;
                }
            }
        }
        __syncthreads();                      // B3: smB (and fsl) ready

        if (g == 0) {
            const int t0 = tile * TILE_T;
            #pragma unroll
            for (int i = 0; i < 2; ++i) {
                const int tb = mh * 32 + i * 16 + q * 4;
                float4 fa = *(const float4*)(smB + tb * 2);
                float4 fb = *(const float4*)(smB + tb * 2 + 4);
                float Ss[4] = { fa.x + fa.y, fa.z + fa.w, fb.x + fb.y, fb.z + fb.w };
                float w0[4], w1[4];
                #pragma unroll
                for (int r = 0; r < 4; ++r) {
                    float f = __builtin_amdgcn_rcpf(Ss[r]);
                    if (t0 + tb + r >= N_) f = 0.f;
                    w0[r] = acc[i][0][r] * f;
                    w1[r] = acc[i][1][r] * f;
                    nrm0 += w0[r];
                    nrm1 += w1[r];
                }
                uint2 p0 = { pk2(w0[0], w0[1]), pk2(w0[2], w0[3]) };
                uint2 p1 = { pk2(w1[0], w1[1]), pk2(w1[2], w1[3]) };
                *(uint2*)(wsl + (nh * 32 + l) * WS_STR      + tb) = p0;
                *(uint2*)(wsl + (nh * 32 + 16 + l) * WS_STR + tb) = p1;
            }
        }
        __syncthreads();                      // B4: wsl ready

        // ---- agg MFMA (v4 layout): wave = (s-strip w4, d-half g)
        #pragma unroll
        for (int ka = 0; ka < 2; ++ka) {
            short8 aw = *(const short8*)(wsl + (w4 * 16 + l) * WS_STR + ka * 32 + q * 8);
            #pragma unroll
            for (int nt = 0; nt < 2; ++nt) {
                short8 bf = *(const short8*)(fsl + (g * 32 + nt * 16 + l) * WS_STR + ka * 32 + q * 8);
                accO[nt] = __builtin_amdgcn_mfma_f32_16x16x32_bf16(aw, bf, accO[nt], 0, 0, 0);
            }
        }
    }

    // ---- endgame: nrm combine across mh through LDS (xs overlay dead)
    __syncthreads();
    if (g == 0) {
        nrm0 += __shfl_xor(nrm0, 16, 64);
        nrm0 += __shfl_xor(nrm0, 32, 64);
        nrm1 += __shfl_xor(nrm1, 16, 64);
        nrm1 += __shfl_xor(nrm1, 32, 64);
        if (lane < 16) {
            u.np[mh][nh * 32 + lane]      = nrm0;
            u.np[mh][nh * 32 + 16 + lane] = nrm1;
        }
    }
    __syncthreads();

    // ---- flush accO (v4 layout): rows s = w4*16+q*4+r, cols d = g*32+nt*16+l
    if (SLAB) {
        float* sp = accg + ((size_t)(b * H_ + h) * PBLK + p) * 4096;
        #pragma unroll
        for (int nt = 0; nt < 2; ++nt)
            #pragma unroll
            for (int r = 0; r < 4; ++r)
                sp[(w4 * 16 + q * 4 + r) * 64 + g * 32 + nt * 16 + l] = accO[nt][r];
        if (wv == 0) {
            float v = u.np[0][lane] + u.np[1][lane];
            nrmg[((b * H_ + h) * PBLK + p) * 64 + lane] = v;
        }
    } else {
        float* ag = accg + (size_t)((b * H_ + h) * 64) * 64;
        #pragma unroll
        for (int nt = 0; nt < 2; ++nt)
            #pragma unroll
            for (int r = 0; r < 4; ++r)
                atomicAdd(ag + (w4 * 16 + q * 4 + r) * 64 + g * 32 + nt * 16 + l, accO[nt][r]);
        if (wv == 0) {
            float v = u.np[0][lane] + u.np[1][lane];
            atomicAdd(nrmg + (b * H_ + h) * 64 + lane, v);
        }
    }
}

// ---------------------------------------------------------------------------
__global__ void finalize_big(const float* __restrict__ slab,
                             const float* __restrict__ nslab,
                             float* __restrict__ out) {
    int idx = blockIdx.x * 256 + threadIdx.x;  // 65536
    int bh = idx >> 12, sd = idx & 4095, s = sd >> 6;
    const float* sp = slab  + (size_t)bh * PBLK * 4096 + sd;
    const float* np = nslab + bh * PBLK * 64 + s;
    float acc = 0.f, nn = 0.f;
    #pragma unroll 8
    for (int p = 0; p < PBLK; ++p) { acc += sp[p * 4096]; nn += np[p * 64]; }
    out[idx] = acc / (nn + 1e-5f);
}

__global__ void finalize_small(const uint8_t* __restrict__ wsb, float* __restrict__ out) {
    int idx = blockIdx.x * 256 + threadIdx.x;
    float a = ((const float*)(wsb + ACC_OFF))[idx];
    float n = ((const float*)(wsb + NRM_OFF))[idx / D_];
    out[idx] = a / (n + 1e-5f);
}

// ---------------------------------------------------------------------------
extern "C" void kernel_launch(void* const* d_in, const int* in_sizes, int n_in,
                              void* d_out, int out_size, void* d_ws, size_t ws_size,
                              hipStream_t stream) {
    const float* x           = (const float*)d_in[0];
    const float* W_x         = (const float*)d_in[1];
    const float* b_x         = (const float*)d_in[2];
    const float* W_fx        = (const float*)d_in[3];
    const float* b_fx        = (const float*)d_in[4];
    const float* W_slice     = (const float*)d_in[5];
    const float* b_slice     = (const float*)d_in[6];
    const float* temperature = (const float*)d_in[7];
    float* out = (float*)d_out;
    uint8_t* wsb = (uint8_t*)d_ws;

    int prep_waves = 2 * H_ * C_ + H_;                 // 4104
    prep_kernel<<<dim3((prep_waves + 3) / 4), dim3(256), 0, stream>>>(
        W_x, b_x, W_fx, W_slice, b_slice, temperature, wsb);

    if (ws_size >= (size_t)WS_BIG_END) {
        main_kernel<true><<<dim3(PBLK * H_ * B_), dim3(512), 0, stream>>>(
            x, b_fx, wsb, (float*)(wsb + SLAB_OFF), (float*)(wsb + NSLAB_OFF));
        finalize_big<<<dim3(256), dim3(256), 0, stream>>>(
            (const float*)(wsb + SLAB_OFF), (const float*)(wsb + NSLAB_OFF), out);
    } else {
        hipMemsetAsync(wsb + ACC_OFF, 0, (B_ * H_ * S_ * D_ + B_ * H_ * S_) * 4, stream);
        main_kernel<false><<<dim3(PBLK * H_ * B_), dim3(512), 0, stream>>>(
            x, b_fx, wsb, (float*)(wsb + ACC_OFF), (float*)(wsb + NRM_OFF));
        finalize_small<<<dim3(256), dim3(256), 0, stream>>>(wsb, out);
    }
}

// Round 6
// 572.020 us; speedup vs baseline: 1.2033x; 1.2033x over previous
//
#include <hip/hip_runtime.h>
#include <hip/hip_bf16.h>
#include <cstdint>

// Problem constants
#define B_     2
#define N_     100000
#define C_     256
#define H_     8
#define D_     64
#define S_     64
#define INNER_ 512

#define TILE_T 64
#define NTILES ((N_ + TILE_T - 1) / TILE_T)   // 1563
#define PBLK   32                             // blocks per (b,h); grid = 32*8*2 = 512 blocks of 512 thr

// Workspace layout (bytes)
#define WEFFT_OFF 0                           // bf16 [H][S][C]   = 262144  (pre-scaled by log2e/temp)
#define WFXT_OFF  262144                      // bf16 [H][D][C]   = 262144
#define BIASE_OFF 524288                      // f32  [H][S]      = 2048    (pre-scaled)
#define SLAB_OFF  526336                      // f32 [B*H][PBLK][4096] = 8388608
#define NSLAB_OFF (SLAB_OFF + B_*H_*PBLK*4096*4)
#define WS_BIG_END (NSLAB_OFF + B_*H_*PBLK*64*4)   // ~9.05 MB
#define ACC_OFF   526336
#define NRM_OFF   (ACC_OFF + B_*H_*S_*D_*4)
#define WS_SMALL_END (NRM_OFF + B_*H_*S_*4)

typedef __attribute__((ext_vector_type(8)))  short short8;
typedef __attribute__((ext_vector_type(4)))  float f32x4;

__device__ inline short f2bf(float f) {
    __hip_bfloat16 h = __float2bfloat16(f);
    short s; __builtin_memcpy(&s, &h, 2); return s;
}
__device__ inline uint32_t pk2(float a, float b) {
    __hip_bfloat162 h = __float22bfloat162_rn(float2{a, b});
    uint32_t u; __builtin_memcpy(&u, &h, 4); return u;
}

// Barrier with LDS-only drain: does NOT drain vmcnt, so in-flight global
// prefetch loads survive across it (their wait happens at true register use,
// compiler-tracked). All in-loop cross-wave state is LDS -> lgkmcnt(0)
// before s_barrier is sufficient. sched_barrier(0) pins ordering (rule #18).
__device__ inline void bar_lgkm() {
    asm volatile("s_waitcnt lgkmcnt(0)" ::: "memory");
    __builtin_amdgcn_sched_barrier(0);
    __builtin_amdgcn_s_barrier();
    __builtin_amdgcn_sched_barrier(0);
}

// ---------------------------------------------------------------------------
// prep: unchanged (v4).
// ---------------------------------------------------------------------------
__global__ void prep_kernel(const float* __restrict__ W_x,
                            const float* __restrict__ b_x,
                            const float* __restrict__ W_fx,
                            const float* __restrict__ W_slice,
                            const float* __restrict__ b_slice,
                            const float* __restrict__ temperature,
                            uint8_t* __restrict__ wsb) {
    int wid  = (blockIdx.x * 256 + threadIdx.x) >> 6;
    int lane = threadIdx.x & 63;
    if (wid < H_ * C_) {
        int h = wid >> 8, k = wid & 255;
        float t = temperature[h]; t = fminf(fmaxf(t, 0.1f), 5.0f);
        float sc = 1.44269504088896f / t;
        const float* wx = W_x + k * INNER_ + h * 64;
        float a = 0.f;
        #pragma unroll 8
        for (int d = 0; d < D_; ++d)
            a = fmaf(wx[d], W_slice[d * 64 + lane], a);
        ((short*)(wsb + WEFFT_OFF))[(h * 64 + lane) * 256 + k] = f2bf(a * sc);
    } else if (wid < 2 * H_ * C_) {
        int j = wid - H_ * C_;
        int h = j >> 8, k = j & 255;
        ((short*)(wsb + WFXT_OFF))[(h * 64 + lane) * 256 + k] =
            f2bf(W_fx[k * INNER_ + h * 64 + lane]);
    } else if (wid < 2 * H_ * C_ + H_) {
        int h = wid - 2 * H_ * C_;
        float t = temperature[h]; t = fminf(fmaxf(t, 0.1f), 5.0f);
        float sc = 1.44269504088896f / t;
        float a = 0.f;
        #pragma unroll 8
        for (int d = 0; d < D_; ++d)
            a = fmaf(b_x[h * 64 + d], W_slice[d * 64 + lane], a);
        ((float*)(wsb + BIASE_OFF))[h * 64 + lane] = (a + b_slice[lane]) * sc;
    }
}

// ---------------------------------------------------------------------------
// main v9 = v4 dataflow VERBATIM (the measured-384-us structure: 16-wide
// n-strips, breg[8]=32 regs, acc[4], 4-wave smB combine) with two structural
// stall-taxes removed:
//   1. xs un-unioned from wsl/fsl -> B1 deleted (3 barriers/tile).
//      Safety: pack(t+1) writes xs; last xs readers (main MFMA of t) finish
//      before B3(t); B3+B4 separate them.
//   2. B3/B4 are raw s_barrier + lgkmcnt(0) only (bar_lgkm): NO vmcnt drain.
//      v4's __syncthreads at B3 force-drained the 8 in-flight prefetch loads
//      (~HBM latency exposed every tile). Loads now wait only at their true
//      consumer (pack, next iteration) -> cover = softmax+norm+agg+loop.
//      No cross-wave global-memory communication exists in-loop, so vmcnt
//      ordering at barriers is unnecessary. B2 stays __syncthreads (free:
//      nothing in flight there; acts as once-per-tile safety net).
// ---------------------------------------------------------------------------
template<bool SLAB>
__global__ __launch_bounds__(512, 4) void main_kernel(
        const float* __restrict__ x,
        const float* __restrict__ b_fx,
        const uint8_t* __restrict__ wsb,
        float* __restrict__ accg,             // slab base or acc base
        float* __restrict__ nrmg) {           // nslab base or nrm base
    __shared__ short xs[TILE_T * 264];        // 33792 B [tok][k] bf16
    __shared__ short wsl[S_ * 72];            // 9216 B  [s][tok] bf16
    __shared__ short fsl[D_ * 72];            // 9216 B  [d][tok] bf16
    __shared__ float smB[TILE_T * 4];         // 1024 B  [tok][wave] partial sumexp

    const int tid = threadIdx.x;
    const int bid = blockIdx.x;
    // XCD swizzle: h = (bid>>3)&7 so all 8 h of a (p,b) group share bid%8 (same XCD)
    const int cc = bid & 7;
    const int h  = (bid >> 3) & 7;
    const int pb = (bid >> 6) * 8 + cc;       // [0,64)
    const int p  = pb & 31;
    const int b  = pb >> 5;

    const int lane = tid & 63, wv = tid >> 6;
    const int l = lane & 15, q = lane >> 4;
    const int g  = wv >> 2;                   // 0: logits (s), 1: fx (d)
    const int w4 = wv & 3;                    // 16-wide n-strip

    // persistent B-frags for my n-strip (8 frags = 32 VGPRs)
    const short* wT = (const short*)(wsb + (g ? WFXT_OFF : WEFFT_OFF)) + h * (64 * 256);
    short8 breg[8];
    #pragma unroll
    for (int k = 0; k < 8; ++k)
        breg[k] = *(const short8*)(wT + (w4 * 16 + l) * 256 + k * 32 + q * 8);

    const float bias_n = g ? b_fx[h * 64 + w4 * 16 + l]
                           : ((const float*)(wsb + BIASE_OFF))[h * 64 + w4 * 16 + l];

    const float* xb = x + (size_t)b * ((size_t)N_ * C_);
    f32x4 accO[2] = {};                       // out [16 s][32 d] strip, persistent
    float nrmacc = 0.f;

    // prologue: prefetch first tile into registers (8 float4 = 32 VGPRs)
    float4 xv[8];
    {
        const int col = lane * 4;
        #pragma unroll
        for (int j = 0; j < 8; ++j) {
            int gt = p * TILE_T + wv + 8 * j;
            xv[j] = (gt < N_) ? *(const float4*)(xb + (size_t)gt * C_ + col)
                              : float4{0.f, 0.f, 0.f, 0.f};
        }
    }

    #pragma unroll 1
    for (int tile = p; tile < NTILES; tile += PBLK) {
        // ---- pack prefetched tile -> xs (bf16). No barrier needed before:
        // all xs reads of tile t-1 completed before B3(t-1), two barriers ago.
        {
            #pragma unroll
            for (int j = 0; j < 8; ++j) {
                int row = wv + 8 * j;
                uint2 pk = { pk2(xv[j].x, xv[j].y), pk2(xv[j].z, xv[j].w) };
                *(uint2*)(xs + row * 264 + lane * 4) = pk;
            }
        }
        __syncthreads();                      // B2: xs ready (full drain ~free here)

        // ---- issue prefetch of NEXT tile; with vmcnt-free B3/B4 these loads
        // stay in flight until consumed by pack(t+1) -> full-loop latency cover
        {
            int nxt = tile + PBLK;
            if (nxt < NTILES) {
                const int col = lane * 4;
                #pragma unroll
                for (int j = 0; j < 8; ++j) {
                    int gt = nxt * TILE_T + wv + 8 * j;
                    xv[j] = (gt < N_) ? *(const float4*)(xb + (size_t)gt * C_ + col)
                                      : float4{0.f, 0.f, 0.f, 0.f};
                }
            }
        }

        // ---- main MFMA GEMM: acc[m] = x_tile @ W(n-strip)
        f32x4 acc[4] = {};
        #pragma unroll
        for (int k = 0; k < 8; ++k) {
            #pragma unroll
            for (int m = 0; m < 4; ++m) {
                short8 a = *(const short8*)(xs + (m * 16 + l) * 264 + k * 32 + q * 8);
                acc[m] = __builtin_amdgcn_mfma_f32_16x16x32_bf16(a, breg[k], acc[m], 0, 0, 0);
            }
        }

        if (g == 0) {
            // logits are pre-scaled to log2 domain: e = exp2(v), no max needed
            #pragma unroll
            for (int m = 0; m < 4; ++m)
                #pragma unroll
                for (int r = 0; r < 4; ++r) {
                    float e = __builtin_amdgcn_exp2f(acc[m][r] + bias_n);
                    acc[m][r] = e;
                    float sv = e;
                    sv += __shfl_xor(sv, 1, 64);
                    sv += __shfl_xor(sv, 2, 64);
                    sv += __shfl_xor(sv, 4, 64);
                    sv += __shfl_xor(sv, 8, 64);
                    if (l == 0) smB[(m * 16 + q * 4 + r) * 4 + wv] = sv;
                }
        } else {
            #pragma unroll
            for (int m = 0; m < 4; ++m)
                #pragma unroll
                for (int r = 0; r < 4; ++r)
                    acc[m][r] += bias_n;
        }
        bar_lgkm();                           // B3: smB ready (no vmcnt drain)

        const int t0 = tile * TILE_T;
        if (g == 0) {
            // combine 4 partial sums, normalize, write w -> wsl
            #pragma unroll
            for (int m = 0; m < 4; ++m) {
                #pragma unroll
                for (int r = 0; r < 4; ++r) {
                    int tok = m * 16 + q * 4 + r;
                    float4 s4 = *(const float4*)(smB + tok * 4);
                    float S = (s4.x + s4.y) + (s4.z + s4.w);
                    float f = __builtin_amdgcn_rcpf(S);
                    if (t0 + tok >= N_) f = 0.f;
                    float w = acc[m][r] * f;
                    acc[m][r] = w;
                    nrmacc += w;
                }
                uint2 pk = { pk2(acc[m][0], acc[m][1]), pk2(acc[m][2], acc[m][3]) };
                *(uint2*)(wsl + (w4 * 16 + l) * 72 + m * 16 + q * 4) = pk;
            }
        } else {
            #pragma unroll
            for (int m = 0; m < 4; ++m) {
                uint2 pk = { pk2(acc[m][0], acc[m][1]), pk2(acc[m][2], acc[m][3]) };
                *(uint2*)(fsl + (w4 * 16 + l) * 72 + m * 16 + q * 4) = pk;
            }
        }
        bar_lgkm();                           // B4: wsl/fsl ready (no vmcnt drain)

        // ---- aggregation MFMA: wave = (s-strip w4, d-half g): accO += w^T @ fx
        #pragma unroll
        for (int kk = 0; kk < 2; ++kk) {
            short8 aw = *(const short8*)(wsl + (w4 * 16 + l) * 72 + kk * 32 + q * 8);
            #pragma unroll
            for (int nt = 0; nt < 2; ++nt) {
                short8 bf = *(const short8*)(fsl + (g * 32 + nt * 16 + l) * 72 + kk * 32 + q * 8);
                accO[nt] = __builtin_amdgcn_mfma_f32_16x16x32_bf16(aw, bf, accO[nt], 0, 0, 0);
            }
        }
    }

    // ---- flush: rows s = w4*16 + q*4 + r, cols d = g*32 + nt*16 + l
    if (SLAB) {
        float* sp = accg + ((size_t)(b * H_ + h) * PBLK + p) * 4096;
        #pragma unroll
        for (int nt = 0; nt < 2; ++nt)
            #pragma unroll
            for (int r = 0; r < 4; ++r)
                sp[(w4 * 16 + q * 4 + r) * 64 + g * 32 + nt * 16 + l] = accO[nt][r];
        if (g == 0) {
            float v = nrmacc;
            v += __shfl_xor(v, 16, 64);
            v += __shfl_xor(v, 32, 64);
            if (lane < 16)
                nrmg[((b * H_ + h) * PBLK + p) * 64 + w4 * 16 + lane] = v;
        }
    } else {
        float* ag = accg + (size_t)((b * H_ + h) * 64) * 64;
        #pragma unroll
        for (int nt = 0; nt < 2; ++nt)
            #pragma unroll
            for (int r = 0; r < 4; ++r)
                atomicAdd(ag + (w4 * 16 + q * 4 + r) * 64 + g * 32 + nt * 16 + l, accO[nt][r]);
        if (g == 0) {
            float v = nrmacc;
            v += __shfl_xor(v, 16, 64);
            v += __shfl_xor(v, 32, 64);
            if (lane < 16)
                atomicAdd(nrmg + (b * H_ + h) * 64 + w4 * 16 + lane, v);
        }
    }
}

// ---------------------------------------------------------------------------
__global__ void finalize_big(const float* __restrict__ slab,
                             const float* __restrict__ nslab,
                             float* __restrict__ out) {
    int idx = blockIdx.x * 256 + threadIdx.x;  // 65536
    int bh = idx >> 12, sd = idx & 4095, s = sd >> 6;
    const float* sp = slab  + (size_t)bh * PBLK * 4096 + sd;
    const float* np = nslab + bh * PBLK * 64 + s;
    float acc = 0.f, nn = 0.f;
    #pragma unroll 8
    for (int p = 0; p < PBLK; ++p) { acc += sp[p * 4096]; nn += np[p * 64]; }
    out[idx] = acc / (nn + 1e-5f);
}

__global__ void finalize_small(const uint8_t* __restrict__ wsb, float* __restrict__ out) {
    int idx = blockIdx.x * 256 + threadIdx.x;
    float a = ((const float*)(wsb + ACC_OFF))[idx];
    float n = ((const float*)(wsb + NRM_OFF))[idx / D_];
    out[idx] = a / (n + 1e-5f);
}

// ---------------------------------------------------------------------------
extern "C" void kernel_launch(void* const* d_in, const int* in_sizes, int n_in,
                              void* d_out, int out_size, void* d_ws, size_t ws_size,
                              hipStream_t stream) {
    const float* x           = (const float*)d_in[0];
    const float* W_x         = (const float*)d_in[1];
    const float* b_x         = (const float*)d_in[2];
    const float* W_fx        = (const float*)d_in[3];
    const float* b_fx        = (const float*)d_in[4];
    const float* W_slice     = (const float*)d_in[5];
    const float* b_slice     = (const float*)d_in[6];
    const float* temperature = (const float*)d_in[7];
    float* out = (float*)d_out;
    uint8_t* wsb = (uint8_t*)d_ws;

    int prep_waves = 2 * H_ * C_ + H_;                 // 4104
    prep_kernel<<<dim3((prep_waves + 3) / 4), dim3(256), 0, stream>>>(
        W_x, b_x, W_fx, W_slice, b_slice, temperature, wsb);

    if (ws_size >= (size_t)WS_BIG_END) {
        main_kernel<true><<<dim3(PBLK * H_ * B_), dim3(512), 0, stream>>>(
            x, b_fx, wsb, (float*)(wsb + SLAB_OFF), (float*)(wsb + NSLAB_OFF));
        finalize_big<<<dim3(256), dim3(256), 0, stream>>>(
            (const float*)(wsb + SLAB_OFF), (const float*)(wsb + NSLAB_OFF), out);
    } else {
        hipMemsetAsync(wsb + ACC_OFF, 0, (B_ * H_ * S_ * D_ + B_ * H_ * S_) * 4, stream);
        main_kernel<false><<<dim3(PBLK * H_ * B_), dim3(512), 0, stream>>>(
            x, b_fx, wsb, (float*)(wsb + ACC_OFF), (float*)(wsb + NRM_OFF));
        finalize_small<<<dim3(256), dim3(256), 0, stream>>>(wsb, out);
    }
}